// Round 2
// baseline (6433.263 us; speedup 1.0000x reference)
//
#include <hip/hip_runtime.h>
#include <hip/hip_bf16.h>

// BiLSTM, B=128 S=1024 D=128 H=256, transpose quirk: u_t[r][k] = x[k,t,r].
// Round 5: R4 still latency-bound at 5.1us/step. Remove the LDS round-trip
// and intra-WG coupling entirely:
//  (a) ZERO LDS / ZERO barriers in bilstm_kernel: each of the 128 waves is an
//      autonomous worker. W x-part + h-part fragments live in registers
//      (xareg 64 + areg 128 VGPR); x B-fragments prefetched one step ahead
//      into regs; h B-fragments loaded DIRECTLY from hbuf into MFMA operands
//      (16x dwordx4 sc0 sc1), issued post-detect, latency hidden under the
//      x-GEMM, released by vmcnt(8) (xf prefetch stays in flight).
//  (b) flags: plain per-wave relaxed stores (value s+1) to 32 words/group;
//      consumer polls with ONE lane-parallel load + __all (no RMW queue, no
//      2xu64 chain, no s_sleep).
//  (c) epilogue order: hbuf stores -> vmcnt(0) -> flag store ->
//      sched_barrier(0) -> out/final stores. The pre-flag drain no longer
//      waits on ~0.5us of scattered output writes.
//  (d) SQ_LDS_BANK_CONFLICT -> ~0 (no LDS in the hot kernel).

typedef unsigned int  u32;
typedef unsigned long long u64;
typedef unsigned short u16;
typedef short short8_t __attribute__((ext_vector_type(8)));
typedef float float4_t __attribute__((ext_vector_type(4)));
typedef int   int4_t   __attribute__((ext_vector_type(4)));

#define S_LEN 1024
#define D_IN  128
#define H_DIM 256
#define B_DIM 128
#define K_DIM 384

// d_ws layout
#define WS_FLAGS_BYTES 524288           // [4 grp][1024 s][32 wave-word] u32
#define WS_HBUF  524288                 // 256 KB h double-buffer (bf16)
#define WS_XBT   786432                 // 32 MB xbt[t][r][k] bf16
#define WS_NEED  (WS_XBT + (size_t)S_LEN * B_DIM * D_IN * 2)

__device__ __forceinline__ u16 f2bf(float f) {
    union { float f; u32 u; } v; v.f = f;
    u32 r = v.u + 0x7fffu + ((v.u >> 16) & 1u);
    return (u16)(r >> 16);
}
__device__ __forceinline__ float sig_f(float x) {
    return __builtin_amdgcn_rcpf(1.f + __expf(-x));
}
__device__ __forceinline__ float tanh_f(float x) {
    return 2.f * sig_f(2.f * x) - 1.f;
}

// ---- pre-pass: xbt[t][r][k] = bf16(x[k][t][r]) ; one WG per t ----
__global__ __launch_bounds__(256, 4)
void tx_kernel(const float* __restrict__ x, u16* __restrict__ xbt)
{
    __shared__ u16 tile[128][136];      // 272 B rows (16B-aligned)
    const int t   = blockIdx.x;
    const int tid = threadIdx.x;
    for (int c = 0; c < 16; ++c) {
        int f = tid + c * 256;          // 0..4095
        int k = f >> 5, q = f & 31;     // k row, r-chunk
        float4_t v = *(const float4_t*)(x + (size_t)k * (S_LEN * D_IN)
                                          + (size_t)t * D_IN + 4 * q);
        tile[4 * q + 0][k] = f2bf(v[0]);
        tile[4 * q + 1][k] = f2bf(v[1]);
        tile[4 * q + 2][k] = f2bf(v[2]);
        tile[4 * q + 3][k] = f2bf(v[3]);
    }
    __syncthreads();
    u16* dst = xbt + (size_t)t * (B_DIM * D_IN);
    for (int c = 0; c < 8; ++c) {
        int f = tid + c * 256;          // 0..2047
        int r = f >> 4, kc = f & 15;
        *(short8_t*)(dst + r * D_IN + kc * 8) = *(const short8_t*)(&tile[r][kc * 8]);
    }
}

__global__ __launch_bounds__(256, 1)
void bilstm_kernel(const float* __restrict__ x,
                   const float* __restrict__ Wf, const float* __restrict__ bf_,
                   const float* __restrict__ Wb, const float* __restrict__ bb_,
                   float* __restrict__ out,
                   u32* __restrict__ flags,   // [4 grp][1024 s][32] (memset 0)
                   u16* __restrict__ hbuf,    // [2 dir][2 par][128 r][256 h] bf16
                   const u16* __restrict__ xbt,
                   int use_xbt)
{
    const int tid = threadIdx.x;
    const int bx  = blockIdx.x;
    const int dir = bx >> 4;              // 0 fwd, 1 bwd
    const int id  = bx & 15;
    const int bg  = id >> 3;              // r-half
    const int hs  = id & 7;               // h-slice
    const int b0  = bg * 64;
    const int h0  = hs * 32;
    const int grp = dir * 2 + bg;

    const float* W    = dir ? Wb : Wf;
    const float* bias = dir ? bb_ : bf_;

    const int lane = tid & 63;
    const int wid  = tid >> 6;            // 4 waves
    const int quad = lane >> 4;
    const int l15  = lane & 15;
    const int hlt  = wid >> 1;            // m-half (16 h rows each)
    const int nh   = wid & 1;             // n-half (32 b cols each)

    // ---- W fragments direct to registers (fp32 -> bf16) ----
    auto WFRAG = [&](int g, int k0) -> short8_t {
        const float* p = W + ((size_t)(g * H_DIM + h0 + hlt * 16 + l15) * K_DIM + k0);
        float4_t v0 = *(const float4_t*)p;
        float4_t v1 = *(const float4_t*)(p + 4);
        short8_t d;
        d[0] = (short)f2bf(v0[0]); d[1] = (short)f2bf(v0[1]);
        d[2] = (short)f2bf(v0[2]); d[3] = (short)f2bf(v0[3]);
        d[4] = (short)f2bf(v1[0]); d[5] = (short)f2bf(v1[1]);
        d[6] = (short)f2bf(v1[2]); d[7] = (short)f2bf(v1[3]);
        return d;
    };
    short8_t xareg[4][4];                 // x-part A (k 0..127)
    short8_t areg[4][8];                  // h-part A (k 128..383)
    #pragma unroll
    for (int g = 0; g < 4; ++g) {
        #pragma unroll
        for (int ks = 0; ks < 4; ++ks)
            xareg[g][ks] = WFRAG(g, ks * 32 + quad * 8);
        #pragma unroll
        for (int ks = 0; ks < 8; ++ks)
            areg[g][ks]  = WFRAG(g, 128 + ks * 32 + quad * 8);
    }

    float bias_r[4][4];
    #pragma unroll
    for (int g = 0; g < 4; ++g)
        #pragma unroll
        for (int i = 0; i < 4; ++i)
            bias_r[g][i] = bias[g * H_DIM + h0 + hlt * 16 + quad * 4 + i];

    float c_st[2][4];
    #pragma unroll
    for (int nt = 0; nt < 2; ++nt)
        #pragma unroll
        for (int i = 0; i < 4; ++i) c_st[nt][i] = 0.f;

    const int myrow0 = b0 + nh * 32 + l15;    // nt=0 B-row; nt=1 adds 16

    // ---- x B-fragment prefetch (one step ahead, registers only) ----
    short8_t xf[8];                           // [nt*4 + ks]
    auto XFRAG = [&](int tt) {
        if (use_xbt) {
            const u16* xs = xbt + (size_t)tt * (B_DIM * D_IN) + quad * 8;
            #pragma unroll
            for (int nt = 0; nt < 2; ++nt)
                #pragma unroll
                for (int ks = 0; ks < 4; ++ks)
                    xf[nt * 4 + ks] =
                        *(const short8_t*)(xs + (myrow0 + nt * 16) * D_IN + ks * 32);
        } else {
            #pragma unroll
            for (int nt = 0; nt < 2; ++nt)
                #pragma unroll
                for (int ks = 0; ks < 4; ++ks) {
                    short8_t d;
                    #pragma unroll
                    for (int e = 0; e < 8; ++e) {
                        int k = ks * 32 + quad * 8 + e;
                        d[e] = (short)f2bf(x[(size_t)k * (S_LEN * D_IN)
                                             + (size_t)tt * D_IN + myrow0 + nt * 16]);
                    }
                    xf[nt * 4 + ks] = d;
                }
        }
    };
    XFRAG(dir ? (S_LEN - 1) : 0);

    u32*       myflag = flags + (size_t)grp * (S_LEN * 32) + hs * 4 + wid;
    const u32* pollw  = flags + (size_t)grp * (S_LEN * 32) + (lane & 31);

    for (int s = 0; s < S_LEN; ++s) {
        const int t = dir ? (S_LEN - 1 - s) : s;

        int4_t hv[16];
        if (s > 0) {
            // ---- detect: one lane-parallel load of the 32 wave-flags ----
            const u32* fw = pollw + (size_t)(s - 1) * 32;
            for (;;) {
                u32 v = __hip_atomic_load(fw, __ATOMIC_RELAXED,
                                          __HIP_MEMORY_SCOPE_AGENT);
                if (__all((int)(v == (u32)s))) break;
            }
            // ---- issue 16 h B-fragment loads (direct hbuf -> regs) ----
            const int par_r = (s - 1) & 1;
            const u16* hb0 = hbuf + ((size_t)((dir * 2 + par_r) * B_DIM + myrow0))
                                    * H_DIM + quad * 8;
            const u16* hb1 = hb0 + 16 * H_DIM;
#define HL(i, base, O) asm volatile("global_load_dwordx4 %0, %1, off offset:" O " sc0 sc1" \
                                    : "=v"(hv[i]) : "v"(base) : "memory")
            HL(0,  hb0, "0");   HL(1,  hb0, "64");  HL(2,  hb0, "128"); HL(3,  hb0, "192");
            HL(4,  hb0, "256"); HL(5,  hb0, "320"); HL(6,  hb0, "384"); HL(7,  hb0, "448");
            HL(8,  hb1, "0");   HL(9,  hb1, "64");  HL(10, hb1, "128"); HL(11, hb1, "192");
            HL(12, hb1, "256"); HL(13, hb1, "320"); HL(14, hb1, "384"); HL(15, hb1, "448");
#undef HL
        }

        // ---- x-part GEMM (registers only) -- hides the h-load latency ----
        float4_t acc[4][2];
        #pragma unroll
        for (int g = 0; g < 4; ++g) {
            acc[g][0] = (float4_t){0.f, 0.f, 0.f, 0.f};
            acc[g][1] = (float4_t){0.f, 0.f, 0.f, 0.f};
        }
        #pragma unroll
        for (int ks = 0; ks < 4; ++ks)
            #pragma unroll
            for (int g = 0; g < 4; ++g) {
                acc[g][0] = __builtin_amdgcn_mfma_f32_16x16x32_bf16(
                    xareg[g][ks], xf[ks],     acc[g][0], 0, 0, 0);
                acc[g][1] = __builtin_amdgcn_mfma_f32_16x16x32_bf16(
                    xareg[g][ks], xf[4 + ks], acc[g][1], 0, 0, 0);
            }

        // ---- prefetch next-step x fragments (after xf consumed; stays in
        //      flight across the vmcnt(8) below) ----
        const bool pf = (s + 1 < S_LEN);
        if (pf) XFRAG(dir ? (S_LEN - 2 - s) : (s + 1));

        // ---- h-part GEMM, B direct from the in-flight loads ----
        if (s > 0) {
            if (pf) asm volatile("s_waitcnt vmcnt(8)" ::: "memory");   // 16 HL done
            else    asm volatile("s_waitcnt vmcnt(0)" ::: "memory");
            __builtin_amdgcn_sched_barrier(0);
            #pragma unroll
            for (int ks = 0; ks < 8; ++ks) {
                short8_t b0f = __builtin_bit_cast(short8_t, hv[ks]);
                short8_t b1f = __builtin_bit_cast(short8_t, hv[8 + ks]);
                #pragma unroll
                for (int g = 0; g < 4; ++g) {
                    acc[g][0] = __builtin_amdgcn_mfma_f32_16x16x32_bf16(
                        areg[g][ks], b0f, acc[g][0], 0, 0, 0);
                    acc[g][1] = __builtin_amdgcn_mfma_f32_16x16x32_bf16(
                        areg[g][ks], b1f, acc[g][1], 0, 0, 0);
                }
            }
        }

        // ---- activations + state update ----
        const int par_w = s & 1;
        u16* hdst = hbuf + ((dir * 2 + par_w) * B_DIM) * H_DIM;
        const int hrow = h0 + hlt * 16 + quad * 4;

        float hv_[2][4], cv_[2][4];
        #pragma unroll
        for (int nt = 0; nt < 2; ++nt)
            #pragma unroll
            for (int i = 0; i < 4; ++i) {
                float zf = acc[0][nt][i] + bias_r[0][i];
                float zi = acc[1][nt][i] + bias_r[1][i];
                float zc = acc[2][nt][i] + bias_r[2][i];
                float zo = acc[3][nt][i] + bias_r[3][i];
                float fg = sig_f(zf);
                float ig = sig_f(zi);
                float og = sig_f(zo);
                float ct = tanh_f(zc);
                float c  = fg * c_st[nt][i] + ig * ct;
                c_st[nt][i] = c;
                hv_[nt][i] = og * tanh_f(c);
                cv_[nt][i] = c;
            }

        // ---- h broadcast FIRST, drain, flag, THEN bulk output stores ----
        #pragma unroll
        for (int nt = 0; nt < 2; ++nt) {
            const int b = b0 + nh * 32 + nt * 16 + l15;
            u64 hp = (u64)f2bf(hv_[nt][0]) | ((u64)f2bf(hv_[nt][1]) << 16)
                   | ((u64)f2bf(hv_[nt][2]) << 32) | ((u64)f2bf(hv_[nt][3]) << 48);
            __hip_atomic_store((u64*)(hdst + b * H_DIM + hrow), hp,
                               __ATOMIC_RELAXED, __HIP_MEMORY_SCOPE_AGENT);
        }
        asm volatile("s_waitcnt vmcnt(0)" ::: "memory");
        if (lane == 0)
            __hip_atomic_store(myflag + (size_t)s * 32, (u32)(s + 1),
                               __ATOMIC_RELAXED, __HIP_MEMORY_SCOPE_AGENT);
        __builtin_amdgcn_sched_barrier(0);

        #pragma unroll
        for (int nt = 0; nt < 2; ++nt) {
            const int b = b0 + nh * 32 + nt * 16 + l15;
            float4_t ho; ho[0]=hv_[nt][0]; ho[1]=hv_[nt][1];
                         ho[2]=hv_[nt][2]; ho[3]=hv_[nt][3];
            *(float4_t*)(out + ((size_t)b * (S_LEN * 2 * H_DIM)
                          + (size_t)t * (2 * H_DIM) + dir * H_DIM + hrow)) = ho;
            if (s == S_LEN - 1) {  // final states (h then c), fp32
                size_t fo = (size_t)67108864 + (size_t)dir * 32768
                          + (size_t)b * H_DIM + hrow;
                *(float4_t*)(out + fo) = ho;
                float4_t co; co[0]=cv_[nt][0]; co[1]=cv_[nt][1];
                             co[2]=cv_[nt][2]; co[3]=cv_[nt][3];
                *(float4_t*)(out + fo + 65536) = co;
            }
        }
    }
}

extern "C" void kernel_launch(void* const* d_in, const int* in_sizes, int n_in,
                              void* d_out, int out_size, void* d_ws, size_t ws_size,
                              hipStream_t stream) {
    (void)in_sizes; (void)n_in; (void)out_size;
    u32* flags = (u32*)d_ws;
    u16* hbuf  = (u16*)((char*)d_ws + WS_HBUF);
    u16* xbt   = (u16*)((char*)d_ws + WS_XBT);
    const int use_xbt = (ws_size >= WS_NEED) ? 1 : 0;
    hipMemsetAsync(d_ws, 0, WS_FLAGS_BYTES, stream);  // flags start at 0
    if (use_xbt)
        tx_kernel<<<dim3(S_LEN), dim3(256), 0, stream>>>((const float*)d_in[0], xbt);
    bilstm_kernel<<<dim3(32), dim3(256), 0, stream>>>(
        (const float*)d_in[0], (const float*)d_in[1], (const float*)d_in[2],
        (const float*)d_in[3], (const float*)d_in[4],
        (float*)d_out, flags, hbuf, xbt, use_xbt);
}